// Round 2
// baseline (86.184 us; speedup 1.0000x reference)
//
#include <hip/hip_runtime.h>

#define BATCH 32
#define SLEN  128
#define EMB   768
#define DIM   1024
#define NW    10

// ws layout (floats): m[32*768] | acc[32] | e_ws[32*1024*2] (interleaved complex)

// K1: m[b][i] = mean_s x[b][s][i]; s-reduction split 4 ways across blockIdx.y.
__global__ void mean_kernel(const float* __restrict__ x, float* __restrict__ m) {
    int eid = blockIdx.x * 256 + threadIdx.x;      // 0 .. 32*768-1
    int b = eid / EMB, i = eid % EMB;
    int s0 = blockIdx.y * 32;
    const float* xp = x + (size_t)b * SLEN * EMB + (size_t)s0 * EMB + i;
    float sum = 0.f;
    #pragma unroll 8
    for (int s = 0; s < 32; ++s) sum += xp[(size_t)s * EMB];
    atomicAdd(&m[eid], sum * (1.0f / SLEN));
}

// K2: 10-qubit statevector circuit, one block per batch, state in LDS.
// Writes full complex e to e_ws (interleaved) and the d_out region per layout flag.
__global__ void __launch_bounds__(512) circuit_kernel(
        const float* __restrict__ m, const float* __restrict__ tx,
        const float* __restrict__ ty, float* __restrict__ e_ws,
        float* __restrict__ e_out, int interleaved) {
    __shared__ float re[DIM], im[DIM];
    __shared__ float cx[NW], sx[NW], cy[NW], sy[NW];
    int b = blockIdx.x, t = threadIdx.x;

    if (t < NW) {
        float a = tx[t]; cx[t] = cosf(a); sx[t] = sinf(a);
        float c = ty[t]; cy[t] = cosf(c); sy[t] = sinf(c);
    }
    for (int i = t; i < DIM; i += 512) {
        re[i] = (i < EMB) ? m[b * EMB + i] : 0.f;
        im[i] = 0.f;
    }
    __syncthreads();

    for (int rep = 0; rep < 3; ++rep) {
        // RX: new0=(c*r0+s*m1)+i(c*m0-s*r1); new1=(c*r1+s*m0)+i(c*m1-s*r0)
        for (int k = 0; k < NW; ++k) {
            int p = 9 - k;
            int i0 = ((t >> p) << (p + 1)) | (t & ((1 << p) - 1));
            int i1 = i0 | (1 << p);
            float c = cx[k], s = sx[k];
            float r0 = re[i0], m0 = im[i0], r1 = re[i1], m1 = im[i1];
            re[i0] = c * r0 + s * m1;  im[i0] = c * m0 - s * r1;
            re[i1] = c * r1 + s * m0;  im[i1] = c * m1 - s * r0;
            __syncthreads();
        }
        // RY: new0 = c*a0 - s*a1; new1 = s*a0 + c*a1 (componentwise re/im)
        for (int k = 0; k < NW; ++k) {
            int p = 9 - k;
            int i0 = ((t >> p) << (p + 1)) | (t & ((1 << p) - 1));
            int i1 = i0 | (1 << p);
            float c = cy[k], s = sy[k];
            float r0 = re[i0], m0 = im[i0], r1 = re[i1], m1 = im[i1];
            re[i0] = c * r0 - s * r1;  im[i0] = c * m0 - s * m1;
            re[i1] = s * r0 + c * r1;  im[i1] = s * m0 + c * m1;
            __syncthreads();
        }
        // CZ ring + CZ(0,9): negate where parity odd
        for (int i = t; i < DIM; i += 512) {
            int par = __popc((i & (i >> 1)) & 0x1FF) + ((i & (i >> 9)) & 1);
            if (par & 1) { re[i] = -re[i]; im[i] = -im[i]; }
        }
        __syncthreads();
    }

    float2* ew = (float2*)e_ws;
    for (int i = t; i < DIM; i += 512) {
        ew[b * DIM + i] = make_float2(re[i], im[i]);
        if (interleaved) {
            ((float2*)e_out)[b * DIM + i] = make_float2(re[i], im[i]);
        } else {
            e_out[b * DIM + i] = re[i];   // harness astype(float32) drops imag
        }
    }
}

// K3: acc[b] += sum over 16 s-rows of ((x_s.u)^2 + (x_s.v)^2) / 128.
// grid (32, 8) x 256; each of 4 waves handles 4 s-rows via shuffle-reduced dots.
__global__ void score_kernel(const float* __restrict__ x, const float* __restrict__ e_ws,
                             float* __restrict__ acc) {
    __shared__ float uL[EMB], vL[EMB];
    __shared__ float part[4];
    int b = blockIdx.x, chunk = blockIdx.y, t = threadIdx.x;
    const float2* ep = (const float2*)e_ws;
    for (int i = t; i < EMB; i += 256) {
        float2 c = ep[b * DIM + i];
        uL[i] = c.x; vL[i] = c.y;
    }
    __syncthreads();

    int w = t >> 6, l = t & 63;
    float local = 0.f;
    for (int si = 0; si < 4; ++si) {
        int s = chunk * 16 + si * 4 + w;
        const float* xr = x + ((size_t)b * SLEN + s) * EMB;
        float du = 0.f, dv = 0.f;
        #pragma unroll
        for (int j = 0; j < 12; ++j) {
            float xv = xr[l + 64 * j];
            du += xv * uL[l + 64 * j];
            dv += xv * vL[l + 64 * j];
        }
        #pragma unroll
        for (int off = 32; off; off >>= 1) {
            du += __shfl_down(du, off, 64);
            dv += __shfl_down(dv, off, 64);
        }
        if (l == 0) local += du * du + dv * dv;
    }
    if (l == 0) part[w] = local;
    __syncthreads();
    if (t == 0)
        atomicAdd(&acc[b], (part[0] + part[1] + part[2] + part[3]) * (1.0f / SLEN));
}

// K4: clip and write scores.
__global__ void finalize_kernel(const float* __restrict__ acc, float* __restrict__ scores) {
    int b = threadIdx.x;
    if (b < BATCH) scores[b] = fminf(fmaxf(acc[b], 0.f), 1.f);
}

extern "C" void kernel_launch(void* const* d_in, const int* in_sizes, int n_in,
                              void* d_out, int out_size, void* d_ws, size_t ws_size,
                              hipStream_t stream) {
    const float* x  = (const float*)d_in[0];
    const float* tx = (const float*)d_in[1];
    const float* ty = (const float*)d_in[2];
    float* out  = (float*)d_out;           // [0,32): scores; [32,...): e (layout per out_size)
    float* m    = (float*)d_ws;            // 32*768
    float* acc  = m + BATCH * EMB;         // 32
    float* e_ws = acc + BATCH;             // 32*1024*2 floats, 8B-aligned (offset 98432 B)

    int e_elems = out_size - BATCH;
    int interleaved = (e_elems >= BATCH * DIM * 2) ? 1 : 0;

    hipMemsetAsync(d_ws, 0, (BATCH * EMB + BATCH) * sizeof(float), stream);
    mean_kernel<<<dim3(96, 4), 256, 0, stream>>>(x, m);
    circuit_kernel<<<BATCH, 512, 0, stream>>>(m, tx, ty, e_ws, out + BATCH, interleaved);
    score_kernel<<<dim3(BATCH, 8), 256, 0, stream>>>(x, e_ws, acc);
    finalize_kernel<<<1, 64, 0, stream>>>(acc, out);
}